// Round 10
// baseline (18.905 us; speedup 1.0000x reference)
//
#include <hip/hip_runtime.h>

// EctTransform: out[b,r,t] = (sum_n sigmoid(100*(lin_r - x[b,n,:].v[:,t]))) / max_{r,t}
// B=16, N=2048, D=3, R=64, T=64.
//
// Round 21: rcp-sharing. r20's model closure: per iter ~104 pk-VALU
// (416 cyc) + 24 trans (8 exp + 16 rcp). If trans = 16-32 cyc/wave64 on
// the shared pipe, trans is 30-50% of pipe time -> the 16 rcps are the
// last reducible block. Scheme: two reciprocals from one rcp:
//   1/a = rcp(ab)*b, 1/b = rcp(ab)*a,  with a,b pre-scaled by EXACT 2^-62
//   (den<=2^120, den>=1 -> all intermediates normal; power-of-2 scaling is
//   exact; adds 2 roundings + shared-rcp error, same class as existing
//   frcp -> absmax ~0.0039 unchanged). Per fraction: -1 rcp, +14 VALU cyc.
//   rcp@16cyc -> neutral (declare roofline next); rcp@32 -> ~-11%.
// Everything else = r20 verbatim (256 blocks x 1024 thr = 1/CU fused
// kernel, relaxed-agent publish, monotone-in-r row-63 max, distributed
// finish).
// Grid: 16b x 8rg x 2s = 256 blocks x 1024 thr (16 waves x 64 pts) = 1/CU.

#define BATCH  16
#define NPTS   2048
#define RES    64
#define NT     64
#define RPER   8
#define NSPLIT 2
#define NWAVES 16
#define WPTS   64                       // points per wave
#define BPTS   1024                     // points per block
#define HPTS   512                      // even/odd halves per block
#define CLAMP30 1073741824.0f           // 2^30
#define MAGIC  0x3A7FC0DEu

typedef float v2f __attribute__((ext_vector_type(2)));

__device__ __forceinline__ float fexp2(float x) { return __builtin_amdgcn_exp2f(x); }
__device__ __forceinline__ float frcp(float x)  { return __builtin_amdgcn_rcpf(x); }
__device__ __forceinline__ v2f fma2(v2f a, v2f b, v2f c) { return __builtin_elementwise_fma(a, b, c); }
__device__ __forceinline__ v2f min2(v2f a, v2f b) { return __builtin_elementwise_min(a, b); }

union pk8 { unsigned long long u; v2f f; };

__global__ __launch_bounds__(1024, 2)
void ect_fused_kernel(const float* __restrict__ x, const float* __restrict__ v,
                      float* __restrict__ part, unsigned int* __restrict__ flags,
                      float* __restrict__ out) {
    const int tid  = threadIdx.x;
    const int lane = tid & 63;          // t
    const int w    = tid >> 6;          // wave (16 per block)
    const int bid  = blockIdx.x;
    const int s    = bid & 1;           // n-chunk of 1024
    const int rg   = (bid >> 1) & 7;    // r-group of 8
    const int b    = bid >> 4;

    __shared__ float xe[HPTS], ye[HPTS], ze[HPTS];   // even points (SoA)
    __shared__ float xo[HPTS], yo[HPTS], zo[HPTS];   // odd points
    __shared__ float red[NWAVES][RPER * 64];         // 32 KB

    {   // all 1024 threads stage one point each
        const float* xb = x + ((size_t)b * NPTS + (size_t)s * BPTS + tid) * 3;
        const float x0 = xb[0], y0 = xb[1], z0 = xb[2];
        const int h = tid >> 1;
        if (tid & 1) { xo[h] = x0; yo[h] = y0; zo[h] = z0; }
        else         { xe[h] = x0; ye[h] = y0; ze[h] = z0; }
    }

    const float K    = 144.26950408889634f;   // 100 * log2(e)
    const float step = 2.0f / 63.0f;
    const float Ks   = K * step;              // 4.58 per r-step

    const float msv0 = K * v[0 * NT + lane];
    const float msv1 = K * v[1 * NT + lane];
    const float msv2 = K * v[2 * NT + lane];
    const float mslin = -K * (-1.0f + step * (float)(rg * RPER));
    const v2f msv0v = {msv0, msv0}, msv1v = {msv1, msv1}, msv2v = {msv2, msv2};
    const v2f mslinv = {mslin, mslin};

    const float c1 = fexp2(-Ks);
    const float c2 = c1 * c1, c3 = c2 * c1, c4 = c3 * c1, c6 = c4 * c2;
    const v2f Cv[4]  = {{1.0f, 1.0f}, {c1, c1}, {c2, c2}, {c3, c3}};
    const v2f C2v[4] = {{1.0f, 1.0f}, {c2, c2}, {c4, c4}, {c6, c6}};
    const v2f ONE = {1.0f, 1.0f};
    const v2f CL30 = {CLAMP30, CLAMP30};
    const v2f C4v  = {c4, c4};
    const v2f M48  = {48.0f, 48.0f};
    const v2f SC62 = {0x1p-62f, 0x1p-62f};    // exact scale for rcp-sharing

    __syncthreads();

    v2f acc[2][4];
#pragma unroll
    for (int g = 0; g < 2; ++g)
#pragma unroll
        for (int j = 0; j < 4; ++j) acc[g][j] = (v2f){0.0f, 0.0f};

#pragma unroll 2
    for (int it = 0; it < WPTS / 8; ++it) {
        const int base = w * (WPTS / 2) + it * 4;     // pair index, wave-uniform
        const v2f xe0 = *(const v2f*)&xe[base],  xe1 = *(const v2f*)&xe[base + 2];
        const v2f ye0 = *(const v2f*)&ye[base],  ye1 = *(const v2f*)&ye[base + 2];
        const v2f ze0 = *(const v2f*)&ze[base],  ze1 = *(const v2f*)&ze[base + 2];
        const v2f xo0 = *(const v2f*)&xo[base],  xo1 = *(const v2f*)&xo[base + 2];
        const v2f yo0 = *(const v2f*)&yo[base],  yo1 = *(const v2f*)&yo[base + 2];
        const v2f zo0 = *(const v2f*)&zo[base],  zo1 = *(const v2f*)&zo[base + 2];

        // dots (packed, 2 points per instr), clamp m<=48
        v2f mE0 = fma2(ze0, msv2v, fma2(ye0, msv1v, fma2(xe0, msv0v, mslinv)));
        v2f mE1 = fma2(ze1, msv2v, fma2(ye1, msv1v, fma2(xe1, msv0v, mslinv)));
        v2f mO0 = fma2(zo0, msv2v, fma2(yo0, msv1v, fma2(xo0, msv0v, mslinv)));
        v2f mO1 = fma2(zo1, msv2v, fma2(yo1, msv1v, fma2(xo1, msv0v, mslinv)));
        mE0 = min2(mE0, M48); mE1 = min2(mE1, M48);
        mO0 = min2(mO0, M48); mO1 = min2(mO1, M48);

        v2f uE0, uE1, uO0, uO1;
        uE0.x = fexp2(mE0.x); uE0.y = fexp2(mE0.y);
        uE1.x = fexp2(mE1.x); uE1.y = fexp2(mE1.y);
        uO0.x = fexp2(mO0.x); uO0.y = fexp2(mO0.y);
        uO1.x = fexp2(mO1.x); uO1.y = fexp2(mO1.y);

        // group bases: g0 clamped to 2^30; g1 = u*c^4 (<= 2^29.7, clamp-free)
        const v2f g0E0 = min2(uE0, CL30), g0E1 = min2(uE1, CL30);
        const v2f g0O0 = min2(uO0, CL30), g0O1 = min2(uO1, CL30);
        const v2f g1E0 = uE0 * C4v, g1E1 = uE1 * C4v;
        const v2f g1O0 = uO0 * C4v, g1O1 = uO1 * C4v;

        // packed pair sums/products: lanes = pairs (p0,p1),(p2,p3) / (p4,p5),(p6,p7)
        const v2f S[2][2] = {{g0E0 + g0O0, g0E1 + g0O1}, {g1E0 + g1O0, g1E1 + g1O1}};
        const v2f P[2][2] = {{g0E0 * g0O0, g0E1 * g0O1}, {g1E0 * g1O0, g1E1 * g1O1}};

#pragma unroll
        for (int g = 0; g < 2; ++g) {
#pragma unroll
            for (int j = 0; j < 4; ++j) {
                const v2f tA = fma2(S[g][0], Cv[j], ONE);
                const v2f dA = fma2(P[g][0], C2v[j], tA);
                const v2f tB = fma2(S[g][1], Cv[j], ONE);
                const v2f dB = fma2(P[g][1], C2v[j], tB);
                const v2f ds = dA + dB;
                const v2f num = fma2(tA, dB, fma2(tB, dA, ds));
                const v2f den = dA * dB;
                // rcp-sharing: one rcp serves both components.
                // den in [1, 2^120]; denS in [2^-62, 2^58] (exact scale);
                // p in [2^-124, 2^116] normal; numS >= 2^-61 (num >= 2).
                const v2f denS = den * SC62;
                const v2f numS = num * SC62;
                const float p  = denS.x * denS.y;
                const float R  = frcp(p);
                const float t1 = numS.x * denS.y;   // /den.x = t1*R
                const float t2 = numS.y * denS.x;   // /den.y = t2*R
                acc[g][j].x = __builtin_fmaf(t1, R, acc[g][j].x);
                acc[g][j].y = __builtin_fmaf(t2, R, acc[g][j].y);
            }
        }
    }

    // block reduce over the 16 waves -> partial [8r][64t]
#pragma unroll
    for (int g = 0; g < 2; ++g)
#pragma unroll
        for (int j = 0; j < 4; ++j)
            red[w][(g * 4 + j) * 64 + lane] = acc[g][j].x + acc[g][j].y;
    __syncthreads();

    // publish: 256 threads, two adjacent cells each, 8B relaxed agent store (MALL)
    if (tid < 256) {
        v2f s2 = {0.0f, 0.0f};
#pragma unroll
        for (int q = 0; q < NWAVES; ++q) {
            const v2f r2 = *(const v2f*)&red[q][2 * tid];
            s2.x += r2.x; s2.y += r2.y;          // same per-cell q-order as r19/r20
        }
        pk8 pw; pw.f = s2;
        unsigned long long* dst = (unsigned long long*)
            &part[((size_t)(b * NSPLIT + s)) * (RES * NT) + rg * 512 + 2 * tid];
        __hip_atomic_store(dst, pw.u, __ATOMIC_RELAXED, __HIP_MEMORY_SCOPE_AGENT);
    }
    __syncthreads();    // drains vmcnt(0): slice stores ack'd at MALL
    if (tid == 0)
        __hip_atomic_store(&flags[b * 16 + rg * 2 + s], MAGIC,
                           __ATOMIC_RELAXED, __HIP_MEMORY_SCOPE_AGENT);

    // ---- distributed finish: wait on 3 flags ((b,7,0),(b,7,1), sibling) ----
    if (tid < 3) {
        const int fi = (tid == 2) ? (b * 16 + rg * 2 + (s ^ 1))
                                  : (b * 16 + 14 + tid);
        while (__hip_atomic_load(&flags[fi],
                                 __ATOMIC_RELAXED, __HIP_MEMORY_SCOPE_AGENT) != MAGIC)
            __builtin_amdgcn_s_sleep(1);
    }
    __syncthreads();

    // max over t of summed row 63 (monotone in r => this IS the global max)
    const size_t pb0 = (size_t)(b * NSPLIT + 0) * (RES * NT);
    const size_t pb1 = (size_t)(b * NSPLIT + 1) * (RES * NT);
    if (tid < 64) {
        float p0, p1;
        p0 = __uint_as_float(__hip_atomic_load((const unsigned int*)&part[pb0 + 4032 + tid],
                                               __ATOMIC_RELAXED, __HIP_MEMORY_SCOPE_AGENT));
        p1 = __uint_as_float(__hip_atomic_load((const unsigned int*)&part[pb1 + 4032 + tid],
                                               __ATOMIC_RELAXED, __HIP_MEMORY_SCOPE_AGENT));
        float m = p0 + p1;
#pragma unroll
        for (int off = 32; off >= 1; off >>= 1)
            m = fmaxf(m, __shfl_xor(m, off, 64));
        if (tid == 0) red[0][0] = m;
    }
    __syncthreads();
    const float rinv = frcp(red[0][0]);

    // finish my half-slice: 128 threads x 2 cells (s=0 -> r+0..3, s=1 -> r+4..7)
    if (tid < 128) {
        const int cell = rg * 512 + s * 256 + 2 * tid;
        pk8 q0, q1;
        q0.u = __hip_atomic_load((const unsigned long long*)&part[pb0 + cell],
                                 __ATOMIC_RELAXED, __HIP_MEMORY_SCOPE_AGENT);
        q1.u = __hip_atomic_load((const unsigned long long*)&part[pb1 + cell],
                                 __ATOMIC_RELAXED, __HIP_MEMORY_SCOPE_AGENT);
        v2f o;
        o.x = (q0.f.x + q1.f.x) * rinv;          // same s0+s1 order as old norm
        o.y = (q0.f.y + q1.f.y) * rinv;
        *(v2f*)&out[(size_t)b * (RES * NT) + cell] = o;
    }
}

extern "C" void kernel_launch(void* const* d_in, const int* in_sizes, int n_in,
                              void* d_out, int out_size, void* d_ws, size_t ws_size,
                              hipStream_t stream) {
    const float* x = (const float*)d_in[0];   // (16, 2048, 3)
    const float* v = (const float*)d_in[1];   // (3, 64)
    float* out  = (float*)d_out;              // (16, 64, 64)
    float* part = (float*)d_ws;               // [16][2][4096] f32 = 512 KB
    unsigned int* flags = (unsigned int*)((char*)d_ws + (size_t)BATCH * NSPLIT * RES * NT * 4);

    ect_fused_kernel<<<BATCH * RPER * NSPLIT, 1024, 0, stream>>>(x, v, part, flags, out);
}

// Round 11
// 18.315 us; speedup vs baseline: 1.0322x; 1.0322x over previous
//
#include <hip/hip_runtime.h>

// EctTransform: out[b,r,t] = (sum_n sigmoid(100*(lin_r - x[b,n,:].v[:,t]))) / max_{r,t}
// B=16, N=2048, D=3, R=64, T=64.
//
// Round 22: REVERT to r20 (best verified: 18.33us). r21's rcp-sharing was
// falsified (+0.57us): back-solved v_rcp_f32 ~ 10 cyc/wave64 effective --
// trans ops are substantially overlapped and were never the bottleneck.
// After 11 single-variable probes (occupancy up/exact, I$, LDS-free,
// scalarization, per-block fixed cost, fusion, rcp halving) and three
// exhaustive re-derivations of the math formulation, the evidence fit is:
// VALU-issue-bound at DVFS-throttled burst clock, no software lever left
// > +-0.3us. r20 structure:
//   - compute: 256 blocks x 1024 thr = 1 block/CU, WPTS=64, unroll 2,
//     packed v2f pair-merge math (clamp m<=48; g0=min(u,2^30); g1=u*c^4).
//   - publish: relaxed agent 8B stores -> MALL; syncthreads drains vmcnt;
//     relaxed agent flag; zero cache-maintenance ops.
//   - finish (distributed): ect monotone in r => global max = row 63 max;
//     each block waits on 3 flags, normalizes its own half-slice.
// Grid: 16b x 8rg x 2s = 256 blocks x 1024 thr (16 waves x 64 pts) = 1/CU.

#define BATCH  16
#define NPTS   2048
#define RES    64
#define NT     64
#define RPER   8
#define NSPLIT 2
#define NWAVES 16
#define WPTS   64                       // points per wave
#define BPTS   1024                     // points per block
#define HPTS   512                      // even/odd halves per block
#define CLAMP30 1073741824.0f           // 2^30
#define MAGIC  0x3A7FC0DEu

typedef float v2f __attribute__((ext_vector_type(2)));

__device__ __forceinline__ float fexp2(float x) { return __builtin_amdgcn_exp2f(x); }
__device__ __forceinline__ float frcp(float x)  { return __builtin_amdgcn_rcpf(x); }
__device__ __forceinline__ v2f fma2(v2f a, v2f b, v2f c) { return __builtin_elementwise_fma(a, b, c); }
__device__ __forceinline__ v2f min2(v2f a, v2f b) { return __builtin_elementwise_min(a, b); }

union pk8 { unsigned long long u; v2f f; };

__global__ __launch_bounds__(1024, 2)
void ect_fused_kernel(const float* __restrict__ x, const float* __restrict__ v,
                      float* __restrict__ part, unsigned int* __restrict__ flags,
                      float* __restrict__ out) {
    const int tid  = threadIdx.x;
    const int lane = tid & 63;          // t
    const int w    = tid >> 6;          // wave (16 per block)
    const int bid  = blockIdx.x;
    const int s    = bid & 1;           // n-chunk of 1024
    const int rg   = (bid >> 1) & 7;    // r-group of 8
    const int b    = bid >> 4;

    __shared__ float xe[HPTS], ye[HPTS], ze[HPTS];   // even points (SoA)
    __shared__ float xo[HPTS], yo[HPTS], zo[HPTS];   // odd points
    __shared__ float red[NWAVES][RPER * 64];         // 32 KB

    {   // all 1024 threads stage one point each
        const float* xb = x + ((size_t)b * NPTS + (size_t)s * BPTS + tid) * 3;
        const float x0 = xb[0], y0 = xb[1], z0 = xb[2];
        const int h = tid >> 1;
        if (tid & 1) { xo[h] = x0; yo[h] = y0; zo[h] = z0; }
        else         { xe[h] = x0; ye[h] = y0; ze[h] = z0; }
    }

    const float K    = 144.26950408889634f;   // 100 * log2(e)
    const float step = 2.0f / 63.0f;
    const float Ks   = K * step;              // 4.58 per r-step

    const float msv0 = K * v[0 * NT + lane];
    const float msv1 = K * v[1 * NT + lane];
    const float msv2 = K * v[2 * NT + lane];
    const float mslin = -K * (-1.0f + step * (float)(rg * RPER));
    const v2f msv0v = {msv0, msv0}, msv1v = {msv1, msv1}, msv2v = {msv2, msv2};
    const v2f mslinv = {mslin, mslin};

    const float c1 = fexp2(-Ks);
    const float c2 = c1 * c1, c3 = c2 * c1, c4 = c3 * c1, c6 = c4 * c2;
    const v2f Cv[4]  = {{1.0f, 1.0f}, {c1, c1}, {c2, c2}, {c3, c3}};
    const v2f C2v[4] = {{1.0f, 1.0f}, {c2, c2}, {c4, c4}, {c6, c6}};
    const v2f ONE = {1.0f, 1.0f};
    const v2f CL30 = {CLAMP30, CLAMP30};
    const v2f C4v  = {c4, c4};
    const v2f M48  = {48.0f, 48.0f};

    __syncthreads();

    v2f acc[2][4];
#pragma unroll
    for (int g = 0; g < 2; ++g)
#pragma unroll
        for (int j = 0; j < 4; ++j) acc[g][j] = (v2f){0.0f, 0.0f};

#pragma unroll 2
    for (int it = 0; it < WPTS / 8; ++it) {
        const int base = w * (WPTS / 2) + it * 4;     // pair index, wave-uniform
        const v2f xe0 = *(const v2f*)&xe[base],  xe1 = *(const v2f*)&xe[base + 2];
        const v2f ye0 = *(const v2f*)&ye[base],  ye1 = *(const v2f*)&ye[base + 2];
        const v2f ze0 = *(const v2f*)&ze[base],  ze1 = *(const v2f*)&ze[base + 2];
        const v2f xo0 = *(const v2f*)&xo[base],  xo1 = *(const v2f*)&xo[base + 2];
        const v2f yo0 = *(const v2f*)&yo[base],  yo1 = *(const v2f*)&yo[base + 2];
        const v2f zo0 = *(const v2f*)&zo[base],  zo1 = *(const v2f*)&zo[base + 2];

        // dots (packed, 2 points per instr), clamp m<=48
        v2f mE0 = fma2(ze0, msv2v, fma2(ye0, msv1v, fma2(xe0, msv0v, mslinv)));
        v2f mE1 = fma2(ze1, msv2v, fma2(ye1, msv1v, fma2(xe1, msv0v, mslinv)));
        v2f mO0 = fma2(zo0, msv2v, fma2(yo0, msv1v, fma2(xo0, msv0v, mslinv)));
        v2f mO1 = fma2(zo1, msv2v, fma2(yo1, msv1v, fma2(xo1, msv0v, mslinv)));
        mE0 = min2(mE0, M48); mE1 = min2(mE1, M48);
        mO0 = min2(mO0, M48); mO1 = min2(mO1, M48);

        v2f uE0, uE1, uO0, uO1;
        uE0.x = fexp2(mE0.x); uE0.y = fexp2(mE0.y);
        uE1.x = fexp2(mE1.x); uE1.y = fexp2(mE1.y);
        uO0.x = fexp2(mO0.x); uO0.y = fexp2(mO0.y);
        uO1.x = fexp2(mO1.x); uO1.y = fexp2(mO1.y);

        // group bases: g0 clamped to 2^30; g1 = u*c^4 (<= 2^29.7, clamp-free)
        const v2f g0E0 = min2(uE0, CL30), g0E1 = min2(uE1, CL30);
        const v2f g0O0 = min2(uO0, CL30), g0O1 = min2(uO1, CL30);
        const v2f g1E0 = uE0 * C4v, g1E1 = uE1 * C4v;
        const v2f g1O0 = uO0 * C4v, g1O1 = uO1 * C4v;

        // packed pair sums/products: lanes = pairs (p0,p1),(p2,p3) / (p4,p5),(p6,p7)
        const v2f S[2][2] = {{g0E0 + g0O0, g0E1 + g0O1}, {g1E0 + g1O0, g1E1 + g1O1}};
        const v2f P[2][2] = {{g0E0 * g0O0, g0E1 * g0O1}, {g1E0 * g1O0, g1E1 * g1O1}};

#pragma unroll
        for (int g = 0; g < 2; ++g) {
#pragma unroll
            for (int j = 0; j < 4; ++j) {
                const v2f tA = fma2(S[g][0], Cv[j], ONE);
                const v2f dA = fma2(P[g][0], C2v[j], tA);
                const v2f tB = fma2(S[g][1], Cv[j], ONE);
                const v2f dB = fma2(P[g][1], C2v[j], tB);
                const v2f ds = dA + dB;
                const v2f num = fma2(tA, dB, fma2(tB, dA, ds));
                const v2f den = dA * dB;
                v2f R; R.x = frcp(den.x); R.y = frcp(den.y);
                acc[g][j] = fma2(num, R, acc[g][j]);
            }
        }
    }

    // block reduce over the 16 waves -> partial [8r][64t]
#pragma unroll
    for (int g = 0; g < 2; ++g)
#pragma unroll
        for (int j = 0; j < 4; ++j)
            red[w][(g * 4 + j) * 64 + lane] = acc[g][j].x + acc[g][j].y;
    __syncthreads();

    // publish: 256 threads, two adjacent cells each, 8B relaxed agent store (MALL)
    if (tid < 256) {
        v2f s2 = {0.0f, 0.0f};
#pragma unroll
        for (int q = 0; q < NWAVES; ++q) {
            const v2f r2 = *(const v2f*)&red[q][2 * tid];
            s2.x += r2.x; s2.y += r2.y;          // same per-cell q-order as r19
        }
        pk8 pw; pw.f = s2;
        unsigned long long* dst = (unsigned long long*)
            &part[((size_t)(b * NSPLIT + s)) * (RES * NT) + rg * 512 + 2 * tid];
        __hip_atomic_store(dst, pw.u, __ATOMIC_RELAXED, __HIP_MEMORY_SCOPE_AGENT);
    }
    __syncthreads();    // drains vmcnt(0): slice stores ack'd at MALL
    if (tid == 0)
        __hip_atomic_store(&flags[b * 16 + rg * 2 + s], MAGIC,
                           __ATOMIC_RELAXED, __HIP_MEMORY_SCOPE_AGENT);

    // ---- distributed finish: wait on 3 flags ((b,7,0),(b,7,1), sibling) ----
    if (tid < 3) {
        const int fi = (tid == 2) ? (b * 16 + rg * 2 + (s ^ 1))
                                  : (b * 16 + 14 + tid);
        while (__hip_atomic_load(&flags[fi],
                                 __ATOMIC_RELAXED, __HIP_MEMORY_SCOPE_AGENT) != MAGIC)
            __builtin_amdgcn_s_sleep(1);
    }
    __syncthreads();

    // max over t of summed row 63 (monotone in r => this IS the global max)
    const size_t pb0 = (size_t)(b * NSPLIT + 0) * (RES * NT);
    const size_t pb1 = (size_t)(b * NSPLIT + 1) * (RES * NT);
    if (tid < 64) {
        float p0, p1;
        p0 = __uint_as_float(__hip_atomic_load((const unsigned int*)&part[pb0 + 4032 + tid],
                                               __ATOMIC_RELAXED, __HIP_MEMORY_SCOPE_AGENT));
        p1 = __uint_as_float(__hip_atomic_load((const unsigned int*)&part[pb1 + 4032 + tid],
                                               __ATOMIC_RELAXED, __HIP_MEMORY_SCOPE_AGENT));
        float m = p0 + p1;
#pragma unroll
        for (int off = 32; off >= 1; off >>= 1)
            m = fmaxf(m, __shfl_xor(m, off, 64));
        if (tid == 0) red[0][0] = m;
    }
    __syncthreads();
    const float rinv = frcp(red[0][0]);

    // finish my half-slice: 128 threads x 2 cells (s=0 -> r+0..3, s=1 -> r+4..7)
    if (tid < 128) {
        const int cell = rg * 512 + s * 256 + 2 * tid;
        pk8 q0, q1;
        q0.u = __hip_atomic_load((const unsigned long long*)&part[pb0 + cell],
                                 __ATOMIC_RELAXED, __HIP_MEMORY_SCOPE_AGENT);
        q1.u = __hip_atomic_load((const unsigned long long*)&part[pb1 + cell],
                                 __ATOMIC_RELAXED, __HIP_MEMORY_SCOPE_AGENT);
        v2f o;
        o.x = (q0.f.x + q1.f.x) * rinv;          // same s0+s1 order as old norm
        o.y = (q0.f.y + q1.f.y) * rinv;
        *(v2f*)&out[(size_t)b * (RES * NT) + cell] = o;
    }
}

extern "C" void kernel_launch(void* const* d_in, const int* in_sizes, int n_in,
                              void* d_out, int out_size, void* d_ws, size_t ws_size,
                              hipStream_t stream) {
    const float* x = (const float*)d_in[0];   // (16, 2048, 3)
    const float* v = (const float*)d_in[1];   // (3, 64)
    float* out  = (float*)d_out;              // (16, 64, 64)
    float* part = (float*)d_ws;               // [16][2][4096] f32 = 512 KB
    unsigned int* flags = (unsigned int*)((char*)d_ws + (size_t)BATCH * NSPLIT * RES * NT * 4);

    ect_fused_kernel<<<BATCH * RPER * NSPLIT, 1024, 0, stream>>>(x, v, part, flags, out);
}